// Round 1
// baseline (1580.799 us; speedup 1.0000x reference)
//
#include <hip/hip_runtime.h>
#include <math.h>

#define BB 48
#define TT 32
#define DD 1024
#define SZ 512
#define NCELLS 528  // 32*33/2

// offsets[k] = sum_{i<k} (T - i) = 32k - k(k-1)/2
__device__ __forceinline__ int off_of(int k) { return TT * k - (k * (k - 1)) / 2; }

// ---------------------------------------------------------------------------
// Leaf: chart_h[:, :32] = unit(relu(x @ w_leaf + b_leaf)); Sarr[leaf] = 0
// One block handles 8 rows of the (1536 x 1024) x (1024 x 512) GEMM.
// ---------------------------------------------------------------------------
__global__ __launch_bounds__(256) void leaf_kernel(
    const float* __restrict__ x, const float* __restrict__ w_leaf,
    const float* __restrict__ b_leaf, float* __restrict__ chart_h,
    float* __restrict__ Sarr)
{
    __shared__ float xt[8][DD];     // 32 KB
    __shared__ float red[8][4];
    const int t = threadIdx.x;
    const int row0 = blockIdx.x * 8;

    #pragma unroll
    for (int r = 0; r < 8; ++r) {
        int kk = t * 4;  // 256 threads * 4 floats = 1024 = DD
        *(float4*)&xt[r][kk] = *(const float4*)&x[(size_t)(row0 + r) * DD + kk];
    }
    __syncthreads();

    const int j0 = t, j1 = t + 256;
    float acc0[8], acc1[8];
    #pragma unroll
    for (int r = 0; r < 8; ++r) { acc0[r] = 0.f; acc1[r] = 0.f; }

    for (int k = 0; k < DD; k += 4) {
        float4 xv[8];
        #pragma unroll
        for (int r = 0; r < 8; ++r) xv[r] = *(const float4*)&xt[r][k];
        #pragma unroll
        for (int kk = 0; kk < 4; ++kk) {
            float w0 = w_leaf[(size_t)(k + kk) * SZ + j0];
            float w1 = w_leaf[(size_t)(k + kk) * SZ + j1];
            #pragma unroll
            for (int r = 0; r < 8; ++r) {
                float xvk = (&xv[r].x)[kk];
                acc0[r] = fmaf(xvk, w0, acc0[r]);
                acc1[r] = fmaf(xvk, w1, acc1[r]);
            }
        }
    }

    const float bc0 = b_leaf[j0], bc1 = b_leaf[j1];
    float h0[8], h1[8];
    #pragma unroll
    for (int r = 0; r < 8; ++r) {
        h0[r] = fmaxf(acc0[r] + bc0, 0.f);
        h1[r] = fmaxf(acc1[r] + bc1, 0.f);
        float sq = h0[r] * h0[r] + h1[r] * h1[r];
        #pragma unroll
        for (int o = 32; o; o >>= 1) sq += __shfl_xor(sq, o);
        if ((t & 63) == 0) red[r][t >> 6] = sq;
    }
    __syncthreads();
    #pragma unroll
    for (int r = 0; r < 8; ++r) {
        int grow = row0 + r;
        int b = grow >> 5, pos = grow & 31;
        float nrm = sqrtf(red[r][0] + red[r][1] + red[r][2] + red[r][3]);
        float inv = 1.f / fmaxf(nrm, 1e-12f);
        size_t base = ((size_t)b * NCELLS + pos) * SZ;
        chart_h[base + j0] = h0[r] * inv;
        chart_h[base + j1] = h1[r] * inv;
        if (t == 0) Sarr[(size_t)b * NCELLS + pos] = 0.f;
    }
}

// ---------------------------------------------------------------------------
// Transform: for every cell of `level`, compute
//   a = h @ w_comp[:512,:],  c = h @ w_comp[512:,:],  u = h @ s_bilinear
// as one (B*L x 512) x (512 x 1536) tiled fp32 GEMM.
// grid = (24 col-tiles, ceil(B*L/64) row-tiles), 256 threads, 64x64 tile.
// ---------------------------------------------------------------------------
__global__ __launch_bounds__(256) void transform_kernel(
    const float* __restrict__ chart_h, const float* __restrict__ w_comp,
    const float* __restrict__ s_bil,
    float* __restrict__ Ao, float* __restrict__ Co, float* __restrict__ Uo,
    int level)
{
    __shared__ float As[32][68];   // k-major (transposed), +4 pad
    __shared__ float Bs[32][64];
    const int L = TT - level;
    const int rows = BB * L;
    const int off = off_of(level);
    const int ct = blockIdx.x;     // 0..23
    const int rt = blockIdx.y;
    const int col0 = (ct & 7) * 64;

    const float* W; float* Out;
    if (ct < 8)       { W = w_comp;                   Out = Ao; }
    else if (ct < 16) { W = w_comp + (size_t)SZ * SZ; Out = Co; }
    else              { W = s_bil;                    Out = Uo; }

    const int t = threadIdx.x;
    const int ar = t >> 3;          // 0..31
    const int ak = (t & 7) * 4;     // 0,4,..,28
    const float* aptr[2];
    #pragma unroll
    for (int p = 0; p < 2; ++p) {
        int g = rt * 64 + ar + p * 32;
        if (g < rows) {
            int b = g / L, pos = g % L;
            aptr[p] = chart_h + ((size_t)b * NCELLS + off + pos) * SZ + ak;
        } else aptr[p] = nullptr;
    }
    const int bk = t >> 4;          // 0..15
    const int bc = (t & 15) * 4;
    const float* bptr = W + (size_t)bk * SZ + col0 + bc;

    const int ty = t >> 4, tx = t & 15;
    float acc[4][4];
    #pragma unroll
    for (int i = 0; i < 4; ++i)
        #pragma unroll
        for (int j = 0; j < 4; ++j) acc[i][j] = 0.f;

    for (int k0 = 0; k0 < SZ; k0 += 32) {
        __syncthreads();
        #pragma unroll
        for (int p = 0; p < 2; ++p) {
            float4 v = make_float4(0.f, 0.f, 0.f, 0.f);
            if (aptr[p]) v = *(const float4*)(aptr[p] + k0);
            As[ak + 0][ar + p * 32] = v.x;
            As[ak + 1][ar + p * 32] = v.y;
            As[ak + 2][ar + p * 32] = v.z;
            As[ak + 3][ar + p * 32] = v.w;
        }
        #pragma unroll
        for (int p = 0; p < 2; ++p) {
            *(float4*)&Bs[bk + p * 16][bc] =
                *(const float4*)(bptr + (size_t)(k0 + p * 16) * SZ);
        }
        __syncthreads();
        #pragma unroll
        for (int k = 0; k < 32; ++k) {
            float4 a4 = *(const float4*)&As[k][ty * 4];
            float4 b4 = *(const float4*)&Bs[k][tx * 4];
            float av[4] = {a4.x, a4.y, a4.z, a4.w};
            float bv[4] = {b4.x, b4.y, b4.z, b4.w};
            #pragma unroll
            for (int i = 0; i < 4; ++i)
                #pragma unroll
                for (int j = 0; j < 4; ++j)
                    acc[i][j] = fmaf(av[i], bv[j], acc[i][j]);
        }
    }

    #pragma unroll
    for (int i = 0; i < 4; ++i) {
        int g = rt * 64 + ty * 4 + i;
        if (g < rows) {
            int b = g / L, pos = g % L;
            float4 v = make_float4(acc[i][0], acc[i][1], acc[i][2], acc[i][3]);
            *(float4*)&Out[((size_t)b * NCELLS + off + pos) * SZ + col0 + tx * 4] = v;
        }
    }
}

// ---------------------------------------------------------------------------
// Combine: one block per (b, pos) at `level`.
//   s_n = u_l . h_r + s_l + s_r ; p = softmax(s) ;
//   hbar = unit( sum_n p_n * relu(a_l + c_r + b_comp) ) ; sbar = sum_n p_n s_n
// ---------------------------------------------------------------------------
__global__ __launch_bounds__(256) void combine_kernel(
    float* __restrict__ chart_h,
    const float* __restrict__ Aarr, const float* __restrict__ Carr,
    const float* __restrict__ Uarr, float* __restrict__ Sarr,
    const float* __restrict__ b_comp, int level)
{
    const int L = TT - level, N = level;
    const int bid = blockIdx.x;
    const int b = bid / L, pos = bid % L;
    const int off = off_of(level);

    __shared__ float s_lds[32], p_lds[32];
    __shared__ int lcell[32], rcell[32];
    __shared__ float red[4];

    const int t = threadIdx.x, lane = t & 63, wave = t >> 6;

    if (t < N) {
        lcell[t] = off_of(t) + pos;
        rcell[t] = off_of(level - t - 1) + pos + t + 1;
    }
    __syncthreads();

    // phase 1: bilinear scores
    for (int n = wave; n < N; n += 4) {
        const float* u  = Uarr    + ((size_t)b * NCELLS + lcell[n]) * SZ;
        const float* hr = chart_h + ((size_t)b * NCELLS + rcell[n]) * SZ;
        float d = 0.f;
        #pragma unroll
        for (int jj = 0; jj < 8; ++jj) {
            int j = lane + jj * 64;
            d = fmaf(u[j], hr[j], d);
        }
        #pragma unroll
        for (int o = 32; o; o >>= 1) d += __shfl_xor(d, o);
        if (lane == 0)
            s_lds[n] = d + Sarr[(size_t)b * NCELLS + lcell[n]]
                         + Sarr[(size_t)b * NCELLS + rcell[n]];
    }
    __syncthreads();

    // phase 1b: softmax over N (wave 0)
    if (wave == 0) {
        float sv = (lane < N) ? s_lds[lane] : -INFINITY;
        float m = sv;
        #pragma unroll
        for (int o = 32; o; o >>= 1) m = fmaxf(m, __shfl_xor(m, o));
        float e = (lane < N) ? expf(sv - m) : 0.f;
        float sum = e;
        #pragma unroll
        for (int o = 32; o; o >>= 1) sum += __shfl_xor(sum, o);
        float p = e / sum;
        if (lane < N) p_lds[lane] = p;
        float sb = (lane < N) ? sv * p : 0.f;
        #pragma unroll
        for (int o = 32; o; o >>= 1) sb += __shfl_xor(sb, o);
        if (lane == 0) Sarr[(size_t)b * NCELLS + off + pos] = sb;
    }
    __syncthreads();

    // phase 2: weighted relu-compose
    const int j0 = t, j1 = t + 256;
    const float bc0 = b_comp[j0], bc1 = b_comp[j1];
    float h0 = 0.f, h1 = 0.f;
    for (int n = 0; n < N; ++n) {
        size_t lbase = ((size_t)b * NCELLS + lcell[n]) * SZ;
        size_t rbase = ((size_t)b * NCELLS + rcell[n]) * SZ;
        float p = p_lds[n];
        float v0 = Aarr[lbase + j0] + Carr[rbase + j0] + bc0;
        float v1 = Aarr[lbase + j1] + Carr[rbase + j1] + bc1;
        h0 = fmaf(p, fmaxf(v0, 0.f), h0);
        h1 = fmaf(p, fmaxf(v1, 0.f), h1);
    }

    float sq = h0 * h0 + h1 * h1;
    #pragma unroll
    for (int o = 32; o; o >>= 1) sq += __shfl_xor(sq, o);
    if (lane == 0) red[wave] = sq;
    __syncthreads();
    float nrm = sqrtf(red[0] + red[1] + red[2] + red[3]);
    float inv = 1.f / fmaxf(nrm, 1e-12f);
    size_t obase = ((size_t)b * NCELLS + off + pos) * SZ;
    chart_h[obase + j0] = h0 * inv;
    chart_h[obase + j1] = h1 * inv;
}

// ---------------------------------------------------------------------------
extern "C" void kernel_launch(void* const* d_in, const int* in_sizes, int n_in,
                              void* d_out, int out_size, void* d_ws, size_t ws_size,
                              hipStream_t stream)
{
    const float* x      = (const float*)d_in[0];
    const float* w_leaf = (const float*)d_in[1];
    const float* b_leaf = (const float*)d_in[2];
    const float* w_comp = (const float*)d_in[3];
    const float* b_comp = (const float*)d_in[4];
    const float* s_bil  = (const float*)d_in[5];
    float* chart_h = (float*)d_out;

    // workspace: A, C, U (each B*NCELLS*SZ f32) + Sarr (B*NCELLS f32) ~ 156 MB
    float* ws   = (float*)d_ws;
    const size_t cellsz = (size_t)BB * NCELLS * SZ;
    float* Aarr = ws;
    float* Carr = Aarr + cellsz;
    float* Uarr = Carr + cellsz;
    float* Sarr = Uarr + cellsz;

    leaf_kernel<<<BB * TT / 8, 256, 0, stream>>>(x, w_leaf, b_leaf, chart_h, Sarr);

    {   // transforms for the leaf level (level 0): rows = 48*32 = 1536
        int rows = BB * TT;
        transform_kernel<<<dim3(24, (rows + 63) / 64), 256, 0, stream>>>(
            chart_h, w_comp, s_bil, Aarr, Carr, Uarr, 0);
    }

    for (int level = 1; level < TT; ++level) {
        int L = TT - level;
        combine_kernel<<<BB * L, 256, 0, stream>>>(
            chart_h, Aarr, Carr, Uarr, Sarr, b_comp, level);
        if (level < TT - 1) {  // top cells are never children
            int rows = BB * L;
            transform_kernel<<<dim3(24, (rows + 63) / 64), 256, 0, stream>>>(
                chart_h, w_comp, s_bil, Aarr, Carr, Uarr, level);
        }
    }
}